// Round 3
// baseline (137.844 us; speedup 1.0000x reference)
//
#include <hip/hip_runtime.h>
#include <hip/hip_bf16.h>

#define T_STEPS 8192
#define NN 64
#define FF 128
#define HH 128
#define OO 128
#define TPB_T 4

typedef _Float16 f16;
typedef __attribute__((ext_vector_type(8))) _Float16 f16x8;
typedef __attribute__((ext_vector_type(4))) _Float16 f16x4;
typedef __attribute__((ext_vector_type(4))) float f32x4;

// LDS pitches chosen for <=2-way bank aliasing on ds_read_b128 (free per m136)
#define XH_PITCH 136   // f16 units; stride 68 dwords -> bank step 4, 2-way
#define H2_PITCH 72    // f16 units; stride 36 dwords -> bank step 4, 2-way
#define NM_PITCH 72    // norm tile in LDS, same geometry

// ---------------- prep: norm (f16) + bc = b_enc @ W_gcn (f32) ----------------
__global__ void prep_norm_kernel(const int* __restrict__ src, const int* __restrict__ dst, int E,
                                 const float* __restrict__ benc, const float* __restrict__ wgcn,
                                 f16* __restrict__ normg, float* __restrict__ bcg)
{
    __shared__ float A[NN * NN];
    __shared__ float din[NN], dout[NN];
    const int tid = threadIdx.x;
    for (int i = tid; i < NN * NN; i += 256) A[i] = 0.0f;
    __syncthreads();
    for (int e = tid; e < E; e += 256) atomicAdd(&A[dst[e] * NN + src[e]], 1.0f);
    __syncthreads();
    if (tid < NN) A[tid * NN + tid] += 1.0f;
    __syncthreads();
    if (tid < NN) {               // deg_in[i] = row sum
        float s = 0.f;
        for (int j = 0; j < NN; ++j) s += A[tid * NN + j];
        din[tid] = s;
    } else if (tid < 2 * NN) {    // deg_out[j] = col sum
        int j = tid - NN;
        float s = 0.f;
        for (int i = 0; i < NN; ++i) s += A[i * NN + j];
        dout[j] = s;
    }
    __syncthreads();
    if (tid < NN) {
        float ri = rsqrtf(din[tid]);
        for (int j = 0; j < NN; ++j)
            normg[tid * NN + j] = (f16)(A[tid * NN + j] * ri * rsqrtf(dout[j]));
    }
    if (tid >= 128) {             // bc[o] = b_enc @ W_gcn
        int o = tid - 128;
        float s = 0.f;
        for (int h = 0; h < HH; ++h) s += benc[h] * wgcn[h * OO + o];
        bcg[o] = s;
    }
}

// ---------------- prep: WcT[o][f] = (W_enc @ W_gcn)^T (f16) ----------------
__global__ void prep_wc_kernel(const float* __restrict__ wenc, const float* __restrict__ wgcn,
                               f16* __restrict__ wctg)
{
    int o = blockIdx.x * 2 + (threadIdx.x >> 7);
    int f = threadIdx.x & 127;
    float s = 0.f;
    for (int h = 0; h < HH; ++h) s += wenc[f * HH + h] * wgcn[h * OO + o];
    wctg[o * FF + f] = (f16)s;
}

// ---------------- fused main: out[t] = norm @ (x[t] @ Wc + 1*bc) + 1*bgcn ----------------
__global__ __launch_bounds__(256, 3) void fused_kernel(
    const float* __restrict__ x, const f16* __restrict__ normg,
    const f16* __restrict__ wctg, const float* __restrict__ bcg,
    const float* __restrict__ bgcn, float* __restrict__ out)
{
    __shared__ f16 xh[NN * XH_PITCH];    // x_t as f16, padded  (17408 B)
    __shared__ f16 h2t[OO * H2_PITCH];   // h2 transposed [col][node] (18432 B)
    __shared__ f16 nsh[NN * NM_PITCH];   // norm staged in LDS (9216 B)

    const int tid = threadIdx.x;
    const int lane = tid & 63;
    const int w = tid >> 6;        // wave 0..3 -> output cols w*32..w*32+31
    const int l15 = lane & 15;
    const int lg = lane >> 4;      // 0..3

    // stage norm into LDS once (covered by the first __syncthreads)
    for (int c = tid; c < (NN * NN) / 8; c += 256) {
        int row = c >> 3, cb = (c & 7) * 8;
        *(f16x8*)(nsh + row * NM_PITCH + cb) = *(const f16x8*)(normg + row * NN + cb);
    }

    // loop-invariant register state (kept small: target 3 waves/SIMD)
    f16x8 wcf[2][4];               // B-frags of Wc for this wave's col slice (32 VGPR)
#pragma unroll
    for (int ct = 0; ct < 2; ++ct)
#pragma unroll
        for (int kk = 0; kk < 4; ++kk)
            wcf[ct][kk] = *(const f16x8*)(wctg + (w * 32 + ct * 16 + l15) * FF + kk * 32 + lg * 8);

    f32x4 bcs[2];                  // bc splat per ct (acc1 init)
#pragma unroll
    for (int ct = 0; ct < 2; ++ct) {
        float v = bcg[w * 32 + ct * 16 + l15];
        bcs[ct][0] = v; bcs[ct][1] = v; bcs[ct][2] = v; bcs[ct][3] = v;
    }
    f32x4 bgf[2];                  // bgcn frag per ct (acc2 init)
#pragma unroll
    for (int ct = 0; ct < 2; ++ct)
        bgf[ct] = *(const f32x4*)(bgcn + w * 32 + ct * 16 + lg * 4);

    const int t0 = blockIdx.x * TPB_T;

    // prologue prefetch of x[t0] into registers (8 x float4; block covers 32 KB)
    float4 ra[8];
    {
        const float4* xp = (const float4*)(x + (size_t)t0 * (NN * FF));
#pragma unroll
        for (int ii = 0; ii < 4; ++ii) {
            int c = tid + 256 * ii;
            ra[2 * ii]     = xp[2 * c];
            ra[2 * ii + 1] = xp[2 * c + 1];
        }
    }

    for (int i = 0; i < TPB_T; ++i) {
        const int t = t0 + i;

        // S1: convert + stage x_t into LDS
#pragma unroll
        for (int ii = 0; ii < 4; ++ii) {
            int c = tid + 256 * ii;
            int row = c >> 4, k0 = (c & 15) * 8;
            float4 a = ra[2 * ii], b = ra[2 * ii + 1];
            f16x8 v;
            v[0] = (f16)a.x; v[1] = (f16)a.y; v[2] = (f16)a.z; v[3] = (f16)a.w;
            v[4] = (f16)b.x; v[5] = (f16)b.y; v[6] = (f16)b.z; v[7] = (f16)b.w;
            *(f16x8*)(xh + row * XH_PITCH + k0) = v;
        }
        __syncthreads();   // xh (and, first iter, nsh) ready for all waves

        // S3: issue next t's global loads early (hide HBM latency under MFMA)
        if (i + 1 < TPB_T) {
            const float4* xq = (const float4*)(x + (size_t)(t + 1) * (NN * FF));
#pragma unroll
            for (int ii = 0; ii < 4; ++ii) {
                int c = tid + 256 * ii;
                ra[2 * ii]     = xq[2 * c];
                ra[2 * ii + 1] = xq[2 * c + 1];
            }
        }

        // S4: matmul1  h2'[64, w-cols] = x_t @ Wc + 1*bc   (bias via acc init)
        f32x4 acc1[4][2];
#pragma unroll
        for (int rt = 0; rt < 4; ++rt)
#pragma unroll
            for (int ct = 0; ct < 2; ++ct)
                acc1[rt][ct] = bcs[ct];
#pragma unroll
        for (int kk = 0; kk < 4; ++kk) {
            f16x8 af[4];
#pragma unroll
            for (int rt = 0; rt < 4; ++rt)
                af[rt] = *(const f16x8*)(xh + (rt * 16 + l15) * XH_PITCH + kk * 32 + lg * 8);
#pragma unroll
            for (int rt = 0; rt < 4; ++rt)
#pragma unroll
                for (int ct = 0; ct < 2; ++ct)
                    acc1[rt][ct] = __builtin_amdgcn_mfma_f32_16x16x32_f16(
                        af[rt], wcf[ct][kk], acc1[rt][ct], 0, 0, 0);
        }
        __syncthreads();   // all waves done reading xh -> safe to overwrite next iter

        // S5: per-wave transpose h2' -> LDS [col][node] (wave-private cols, no barrier)
#pragma unroll
        for (int rt = 0; rt < 4; ++rt)
#pragma unroll
            for (int ct = 0; ct < 2; ++ct) {
                f16x4 hv;
#pragma unroll
                for (int r = 0; r < 4; ++r) hv[r] = (f16)acc1[rt][ct][r];
                *(f16x4*)(h2t + (w * 32 + ct * 16 + l15) * H2_PITCH + rt * 16 + lg * 4) = hv;
            }

        // S7: matmul2 swapped: D = h2'^T * norm^T  (lane -> 4 consecutive out cols)
        f32x4 acc2[2][4];
#pragma unroll
        for (int ct = 0; ct < 2; ++ct)
#pragma unroll
            for (int rt = 0; rt < 4; ++rt)
                acc2[ct][rt] = bgf[ct];
#pragma unroll
        for (int kk = 0; kk < 2; ++kk) {
            f16x8 bf[2];
#pragma unroll
            for (int ct = 0; ct < 2; ++ct)
                bf[ct] = *(const f16x8*)(h2t + (w * 32 + ct * 16 + l15) * H2_PITCH + kk * 32 + lg * 8);
            f16x8 nl[4];
#pragma unroll
            for (int rt = 0; rt < 4; ++rt)
                nl[rt] = *(const f16x8*)(nsh + (rt * 16 + l15) * NM_PITCH + kk * 32 + lg * 8);
#pragma unroll
            for (int ct = 0; ct < 2; ++ct)
#pragma unroll
                for (int rt = 0; rt < 4; ++rt)
                    acc2[ct][rt] = __builtin_amdgcn_mfma_f32_16x16x32_f16(
                        bf[ct], nl[rt], acc2[ct][rt], 0, 0, 0);
        }

        // epilogue: store fp32 as float4 (full 128B line per row per wave)
        float* op = out + (size_t)t * (NN * OO);
#pragma unroll
        for (int rt = 0; rt < 4; ++rt)
#pragma unroll
            for (int ct = 0; ct < 2; ++ct)
                *(f32x4*)(op + (rt * 16 + l15) * OO + w * 32 + ct * 16 + lg * 4) = acc2[ct][rt];
    }
}

extern "C" void kernel_launch(void* const* d_in, const int* in_sizes, int n_in,
                              void* d_out, int out_size, void* d_ws, size_t ws_size,
                              hipStream_t stream)
{
    const float* x    = (const float*)d_in[0];
    const float* wenc = (const float*)d_in[1];
    const float* benc = (const float*)d_in[2];
    const float* wgcn = (const float*)d_in[3];
    const float* bgcn = (const float*)d_in[4];
    const int*   src  = (const int*)d_in[5];
    const int*   dst  = (const int*)d_in[6];
    const int E = in_sizes[5];

    // workspace layout: WcT f16 [128*128] (32768 B) | norm f16 [64*64] (8192 B) | bc f32 [128] (512 B)
    f16*   wctg  = (f16*)d_ws;
    f16*   normg = (f16*)((char*)d_ws + 32768);
    float* bcg   = (float*)((char*)d_ws + 32768 + 8192);

    prep_norm_kernel<<<1, 256, 0, stream>>>(src, dst, E, benc, wgcn, normg, bcg);
    prep_wc_kernel<<<OO / 2, 256, 0, stream>>>(wenc, wgcn, wctg);
    fused_kernel<<<T_STEPS / TPB_T, 256, 0, stream>>>(x, normg, wctg, bcg, bgcn, (float*)d_out);
}

// Round 4
// 130.225 us; speedup vs baseline: 1.0585x; 1.0585x over previous
//
#include <hip/hip_runtime.h>
#include <hip/hip_bf16.h>

#define T_STEPS 8192
#define NN 64
#define FF 128
#define HH 128
#define OO 128
#define TPB_T 8

typedef _Float16 f16;
typedef __attribute__((ext_vector_type(8))) _Float16 f16x8;
typedef __attribute__((ext_vector_type(4))) _Float16 f16x4;
typedef __attribute__((ext_vector_type(4))) float f32x4;

// LDS pitches chosen for <=2-way bank aliasing on ds_read_b128 (free per m136)
#define XH_PITCH 136   // f16 units; stride 68 dwords -> bank step 4, 2-way
#define H2_PITCH 72    // f16 units; stride 36 dwords -> bank step 4, 2-way
#define NM_PITCH 72    // norm tile in LDS, same geometry

// ---------------- prep: norm (f16) + bc = b_enc @ W_gcn (f32) ----------------
__global__ void prep_norm_kernel(const int* __restrict__ src, const int* __restrict__ dst, int E,
                                 const float* __restrict__ benc, const float* __restrict__ wgcn,
                                 f16* __restrict__ normg, float* __restrict__ bcg)
{
    __shared__ float A[NN * NN];
    __shared__ float din[NN], dout[NN];
    const int tid = threadIdx.x;
    for (int i = tid; i < NN * NN; i += 256) A[i] = 0.0f;
    __syncthreads();
    for (int e = tid; e < E; e += 256) atomicAdd(&A[dst[e] * NN + src[e]], 1.0f);
    __syncthreads();
    if (tid < NN) A[tid * NN + tid] += 1.0f;
    __syncthreads();
    if (tid < NN) {               // deg_in[i] = row sum
        float s = 0.f;
        for (int j = 0; j < NN; ++j) s += A[tid * NN + j];
        din[tid] = s;
    } else if (tid < 2 * NN) {    // deg_out[j] = col sum
        int j = tid - NN;
        float s = 0.f;
        for (int i = 0; i < NN; ++i) s += A[i * NN + j];
        dout[j] = s;
    }
    __syncthreads();
    if (tid < NN) {
        float ri = rsqrtf(din[tid]);
        for (int j = 0; j < NN; ++j)
            normg[tid * NN + j] = (f16)(A[tid * NN + j] * ri * rsqrtf(dout[j]));
    }
    if (tid >= 128) {             // bc[o] = b_enc @ W_gcn
        int o = tid - 128;
        float s = 0.f;
        for (int h = 0; h < HH; ++h) s += benc[h] * wgcn[h * OO + o];
        bcg[o] = s;
    }
}

// ---------------- prep: WcT[o][f] = (W_enc @ W_gcn)^T (f16) ----------------
__global__ void prep_wc_kernel(const float* __restrict__ wenc, const float* __restrict__ wgcn,
                               f16* __restrict__ wctg)
{
    int o = blockIdx.x * 2 + (threadIdx.x >> 7);
    int f = threadIdx.x & 127;
    float s = 0.f;
    for (int h = 0; h < HH; ++h) s += wenc[f * HH + h] * wgcn[h * OO + o];
    wctg[o * FF + f] = (f16)s;
}

// ---------------- fused main: out[t] = norm @ (x[t] @ Wc + 1*bc) + 1*bgcn ----------------
__global__ __launch_bounds__(256, 2) void fused_kernel(
    const float* __restrict__ x, const f16* __restrict__ normg,
    const f16* __restrict__ wctg, const float* __restrict__ bcg,
    const float* __restrict__ bgcn, float* __restrict__ out)
{
    __shared__ f16 xh[NN * XH_PITCH];    // x_t as f16, padded  (17408 B)
    __shared__ f16 h2t[OO * H2_PITCH];   // h2 transposed [col][node] (18432 B)
    __shared__ f16 nsh[NN * NM_PITCH];   // norm staged in LDS (9216 B)

    const int tid = threadIdx.x;
    const int lane = tid & 63;
    const int w = tid >> 6;        // wave 0..3 -> output cols w*32..w*32+31
    const int l15 = lane & 15;
    const int lg = lane >> 4;      // 0..3

    // stage norm into LDS once (covered by the first __syncthreads)
    for (int c = tid; c < (NN * NN) / 8; c += 256) {
        int row = c >> 3, cb = (c & 7) * 8;
        *(f16x8*)(nsh + row * NM_PITCH + cb) = *(const f16x8*)(normg + row * NN + cb);
    }

    // loop-invariant register state
    f16x8 wcf[2][4];               // B-frags of Wc for this wave's col slice (32 VGPR)
#pragma unroll
    for (int ct = 0; ct < 2; ++ct)
#pragma unroll
        for (int kk = 0; kk < 4; ++kk)
            wcf[ct][kk] = *(const f16x8*)(wctg + (w * 32 + ct * 16 + l15) * FF + kk * 32 + lg * 8);

    f32x4 bcs[2];                  // bc splat per ct (acc1 init)
#pragma unroll
    for (int ct = 0; ct < 2; ++ct) {
        float v = bcg[w * 32 + ct * 16 + l15];
        bcs[ct][0] = v; bcs[ct][1] = v; bcs[ct][2] = v; bcs[ct][3] = v;
    }
    f32x4 bgf[2];                  // bgcn frag per ct (acc2 init)
#pragma unroll
    for (int ct = 0; ct < 2; ++ct)
        bgf[ct] = *(const f32x4*)(bgcn + w * 32 + ct * 16 + lg * 4);

    const int t0 = blockIdx.x * TPB_T;

    // depth-2 register prefetch: two named buffers (rule #20: no runtime indexing)
    float4 raA[8], raB[8];
    {
        const float4* xp0 = (const float4*)(x + (size_t)t0 * (NN * FF));
        const float4* xp1 = xp0 + (NN * FF) / 4;
#pragma unroll
        for (int ii = 0; ii < 4; ++ii) {
            int c = tid + 256 * ii;
            raA[2 * ii]     = xp0[2 * c];
            raA[2 * ii + 1] = xp0[2 * c + 1];
        }
#pragma unroll
        for (int ii = 0; ii < 4; ++ii) {
            int c = tid + 256 * ii;
            raB[2 * ii]     = xp1[2 * c];
            raB[2 * ii + 1] = xp1[2 * c + 1];
        }
    }

    // one t-iteration: consume `rau`, refill it for t+2 (issued right after the
    // staging barrier so the loads fly under ~2 iterations of compute)
    auto body = [&](float4 (&rau)[8], int i) {
        const int t = t0 + i;

        // S1: convert + stage x_t into LDS (counted vmcnt: waits only rau's 8 loads)
#pragma unroll
        for (int ii = 0; ii < 4; ++ii) {
            int c = tid + 256 * ii;
            int row = c >> 4, k0 = (c & 15) * 8;
            float4 a = rau[2 * ii], b = rau[2 * ii + 1];
            f16x8 v;
            v[0] = (f16)a.x; v[1] = (f16)a.y; v[2] = (f16)a.z; v[3] = (f16)a.w;
            v[4] = (f16)b.x; v[5] = (f16)b.y; v[6] = (f16)b.z; v[7] = (f16)b.w;
            *(f16x8*)(xh + row * XH_PITCH + k0) = v;
        }
        __syncthreads();   // xh (and, first iter, nsh) ready for all waves

        // S3: refill rau for t+2 (depth-2 prefetch)
        if (i + 2 < TPB_T) {
            const float4* xq = (const float4*)(x + (size_t)(t + 2) * (NN * FF));
#pragma unroll
            for (int ii = 0; ii < 4; ++ii) {
                int c = tid + 256 * ii;
                rau[2 * ii]     = xq[2 * c];
                rau[2 * ii + 1] = xq[2 * c + 1];
            }
        }

        // S4: matmul1  h2'[64, w-cols] = x_t @ Wc + 1*bc   (bias via acc init)
        f32x4 acc1[4][2];
#pragma unroll
        for (int rt = 0; rt < 4; ++rt)
#pragma unroll
            for (int ct = 0; ct < 2; ++ct)
                acc1[rt][ct] = bcs[ct];
#pragma unroll
        for (int kk = 0; kk < 4; ++kk) {
            f16x8 af[4];
#pragma unroll
            for (int rt = 0; rt < 4; ++rt)
                af[rt] = *(const f16x8*)(xh + (rt * 16 + l15) * XH_PITCH + kk * 32 + lg * 8);
#pragma unroll
            for (int rt = 0; rt < 4; ++rt)
#pragma unroll
                for (int ct = 0; ct < 2; ++ct)
                    acc1[rt][ct] = __builtin_amdgcn_mfma_f32_16x16x32_f16(
                        af[rt], wcf[ct][kk], acc1[rt][ct], 0, 0, 0);
        }
        __syncthreads();   // all waves done reading xh -> safe to overwrite next iter

        // S5: per-wave transpose h2' -> LDS [col][node] (wave-private cols, no barrier)
#pragma unroll
        for (int rt = 0; rt < 4; ++rt)
#pragma unroll
            for (int ct = 0; ct < 2; ++ct) {
                f16x4 hv;
#pragma unroll
                for (int r = 0; r < 4; ++r) hv[r] = (f16)acc1[rt][ct][r];
                *(f16x4*)(h2t + (w * 32 + ct * 16 + l15) * H2_PITCH + rt * 16 + lg * 4) = hv;
            }

        // S7: matmul2 swapped: D = h2'^T * norm^T  (lane -> 4 consecutive out cols)
        f32x4 acc2[2][4];
#pragma unroll
        for (int ct = 0; ct < 2; ++ct)
#pragma unroll
            for (int rt = 0; rt < 4; ++rt)
                acc2[ct][rt] = bgf[ct];
#pragma unroll
        for (int kk = 0; kk < 2; ++kk) {
            f16x8 bf[2];
#pragma unroll
            for (int ct = 0; ct < 2; ++ct)
                bf[ct] = *(const f16x8*)(h2t + (w * 32 + ct * 16 + l15) * H2_PITCH + kk * 32 + lg * 8);
            f16x8 nl[4];
#pragma unroll
            for (int rt = 0; rt < 4; ++rt)
                nl[rt] = *(const f16x8*)(nsh + (rt * 16 + l15) * NM_PITCH + kk * 32 + lg * 8);
#pragma unroll
            for (int ct = 0; ct < 2; ++ct)
#pragma unroll
                for (int rt = 0; rt < 4; ++rt)
                    acc2[ct][rt] = __builtin_amdgcn_mfma_f32_16x16x32_f16(
                        bf[ct], nl[rt], acc2[ct][rt], 0, 0, 0);
        }

        // epilogue: store fp32 as float4 (full 128B line per row per wave)
        float* op = out + (size_t)t * (NN * OO);
#pragma unroll
        for (int rt = 0; rt < 4; ++rt)
#pragma unroll
            for (int ct = 0; ct < 2; ++ct)
                *(f32x4*)(op + (rt * 16 + l15) * OO + w * 32 + ct * 16 + lg * 4) = acc2[ct][rt];
    };

#pragma unroll 1
    for (int i = 0; i < TPB_T; i += 2) {
        body(raA, i);
        body(raB, i + 1);
    }
}

extern "C" void kernel_launch(void* const* d_in, const int* in_sizes, int n_in,
                              void* d_out, int out_size, void* d_ws, size_t ws_size,
                              hipStream_t stream)
{
    const float* x    = (const float*)d_in[0];
    const float* wenc = (const float*)d_in[1];
    const float* benc = (const float*)d_in[2];
    const float* wgcn = (const float*)d_in[3];
    const float* bgcn = (const float*)d_in[4];
    const int*   src  = (const int*)d_in[5];
    const int*   dst  = (const int*)d_in[6];
    const int E = in_sizes[5];

    // workspace layout: WcT f16 [128*128] (32768 B) | norm f16 [64*64] (8192 B) | bc f32 [128] (512 B)
    f16*   wctg  = (f16*)d_ws;
    f16*   normg = (f16*)((char*)d_ws + 32768);
    float* bcg   = (float*)((char*)d_ws + 32768 + 8192);

    prep_norm_kernel<<<1, 256, 0, stream>>>(src, dst, E, benc, wgcn, normg, bcg);
    prep_wc_kernel<<<OO / 2, 256, 0, stream>>>(wenc, wgcn, wctg);
    fused_kernel<<<T_STEPS / TPB_T, 256, 0, stream>>>(x, normg, wctg, bcg, bgcn, (float*)d_out);
}

// Round 5
// 129.048 us; speedup vs baseline: 1.0682x; 1.0091x over previous
//
#include <hip/hip_runtime.h>
#include <hip/hip_bf16.h>

#define T_STEPS 8192
#define NN 64
#define FF 128
#define HH 128
#define OO 128
#define TPB_T 8

typedef _Float16 f16;
typedef __attribute__((ext_vector_type(8))) _Float16 f16x8;
typedef __attribute__((ext_vector_type(4))) _Float16 f16x4;
typedef __attribute__((ext_vector_type(4))) float f32x4;

// LDS pitches chosen for <=2-way bank aliasing on ds_read_b128 (free per m136)
#define XH_PITCH 136   // f16 units; stride 68 dwords -> bank step 4, 2-way
#define H2_PITCH 72    // f16 units; stride 36 dwords -> bank step 4, 2-way
#define NM_PITCH 72    // norm tile in LDS, same geometry

// Raw barrier WITHOUT the vmcnt(0) drain that __syncthreads() emits.
// These barriers only protect LDS producer->consumer, so lgkmcnt(0) suffices;
// global loads/stores legitimately stay in flight across them.
#define BAR_LDS() do {                                        \
    __builtin_amdgcn_sched_barrier(0);                        \
    asm volatile("s_waitcnt lgkmcnt(0)" ::: "memory");        \
    __builtin_amdgcn_s_barrier();                             \
    __builtin_amdgcn_sched_barrier(0);                        \
} while (0)

// ---------------- prep: norm (f16) + bc = b_enc @ W_gcn (f32) ----------------
__global__ void prep_norm_kernel(const int* __restrict__ src, const int* __restrict__ dst, int E,
                                 const float* __restrict__ benc, const float* __restrict__ wgcn,
                                 f16* __restrict__ normg, float* __restrict__ bcg)
{
    __shared__ float A[NN * NN];
    __shared__ float din[NN], dout[NN];
    const int tid = threadIdx.x;
    for (int i = tid; i < NN * NN; i += 256) A[i] = 0.0f;
    __syncthreads();
    for (int e = tid; e < E; e += 256) atomicAdd(&A[dst[e] * NN + src[e]], 1.0f);
    __syncthreads();
    if (tid < NN) A[tid * NN + tid] += 1.0f;
    __syncthreads();
    if (tid < NN) {               // deg_in[i] = row sum
        float s = 0.f;
        for (int j = 0; j < NN; ++j) s += A[tid * NN + j];
        din[tid] = s;
    } else if (tid < 2 * NN) {    // deg_out[j] = col sum
        int j = tid - NN;
        float s = 0.f;
        for (int i = 0; i < NN; ++i) s += A[i * NN + j];
        dout[j] = s;
    }
    __syncthreads();
    if (tid < NN) {
        float ri = rsqrtf(din[tid]);
        for (int j = 0; j < NN; ++j)
            normg[tid * NN + j] = (f16)(A[tid * NN + j] * ri * rsqrtf(dout[j]));
    }
    if (tid >= 128) {             // bc[o] = b_enc @ W_gcn
        int o = tid - 128;
        float s = 0.f;
        for (int h = 0; h < HH; ++h) s += benc[h] * wgcn[h * OO + o];
        bcg[o] = s;
    }
}

// ---------------- prep: WcT[o][f] = (W_enc @ W_gcn)^T (f16) ----------------
__global__ void prep_wc_kernel(const float* __restrict__ wenc, const float* __restrict__ wgcn,
                               f16* __restrict__ wctg)
{
    int o = blockIdx.x * 2 + (threadIdx.x >> 7);
    int f = threadIdx.x & 127;
    float s = 0.f;
    for (int h = 0; h < HH; ++h) s += wenc[f * HH + h] * wgcn[h * OO + o];
    wctg[o * FF + f] = (f16)s;
}

// ---------------- fused main: out[t] = norm @ (x[t] @ Wc + 1*bc) + 1*bgcn ----------------
__global__ __launch_bounds__(256, 2) void fused_kernel(
    const float* __restrict__ x, const f16* __restrict__ normg,
    const f16* __restrict__ wctg, const float* __restrict__ bcg,
    const float* __restrict__ bgcn, float* __restrict__ out)
{
    __shared__ f16 xh[NN * XH_PITCH];    // x_t as f16, padded  (17408 B)
    __shared__ f16 h2t[OO * H2_PITCH];   // h2 transposed [col][node] (18432 B)
    __shared__ f16 nsh[NN * NM_PITCH];   // norm staged in LDS (9216 B)

    const int tid = threadIdx.x;
    const int lane = tid & 63;
    const int w = tid >> 6;        // wave 0..3 -> output cols w*32..w*32+31
    const int l15 = lane & 15;
    const int lg = lane >> 4;      // 0..3

    // stage norm into LDS once (covered by the first barrier)
    for (int c = tid; c < (NN * NN) / 8; c += 256) {
        int row = c >> 3, cb = (c & 7) * 8;
        *(f16x8*)(nsh + row * NM_PITCH + cb) = *(const f16x8*)(normg + row * NN + cb);
    }

    // loop-invariant register state
    f16x8 wcf[2][4];               // B-frags of Wc for this wave's col slice (32 VGPR)
#pragma unroll
    for (int ct = 0; ct < 2; ++ct)
#pragma unroll
        for (int kk = 0; kk < 4; ++kk)
            wcf[ct][kk] = *(const f16x8*)(wctg + (w * 32 + ct * 16 + l15) * FF + kk * 32 + lg * 8);

    f32x4 bcs[2];                  // bc splat per ct (acc1 init)
#pragma unroll
    for (int ct = 0; ct < 2; ++ct) {
        float v = bcg[w * 32 + ct * 16 + l15];
        bcs[ct][0] = v; bcs[ct][1] = v; bcs[ct][2] = v; bcs[ct][3] = v;
    }
    f32x4 bgf[2];                  // bgcn frag per ct (acc2 init)
#pragma unroll
    for (int ct = 0; ct < 2; ++ct)
        bgf[ct] = *(const f32x4*)(bgcn + w * 32 + ct * 16 + lg * 4);

    const int t0 = blockIdx.x * TPB_T;

    // depth-2 register prefetch: two named buffers (rule #20: no runtime indexing)
    float4 raA[8], raB[8];
    {
        const float4* xp0 = (const float4*)(x + (size_t)t0 * (NN * FF));
        const float4* xp1 = xp0 + (NN * FF) / 4;
#pragma unroll
        for (int ii = 0; ii < 4; ++ii) {
            int c = tid + 256 * ii;
            raA[2 * ii]     = xp0[2 * c];
            raA[2 * ii + 1] = xp0[2 * c + 1];
        }
#pragma unroll
        for (int ii = 0; ii < 4; ++ii) {
            int c = tid + 256 * ii;
            raB[2 * ii]     = xp1[2 * c];
            raB[2 * ii + 1] = xp1[2 * c + 1];
        }
    }

    // one t-iteration: consume `rau`, refill it for t+2
    auto body = [&](float4 (&rau)[8], int i) {
        const int t = t0 + i;

        // S1: convert + stage x_t into LDS (counted vmcnt wait on rau only)
#pragma unroll
        for (int ii = 0; ii < 4; ++ii) {
            int c = tid + 256 * ii;
            int row = c >> 4, k0 = (c & 15) * 8;
            float4 a = rau[2 * ii], b = rau[2 * ii + 1];
            f16x8 v;
            v[0] = (f16)a.x; v[1] = (f16)a.y; v[2] = (f16)a.z; v[3] = (f16)a.w;
            v[4] = (f16)b.x; v[5] = (f16)b.y; v[6] = (f16)b.z; v[7] = (f16)b.w;
            *(f16x8*)(xh + row * XH_PITCH + k0) = v;
        }
        BAR_LDS();         // xh (and, first iter, nsh) ready — NO vmcnt drain

        // S3: refill rau for t+2 (stays in flight across the next barriers)
        if (i + 2 < TPB_T) {
            const float4* xq = (const float4*)(x + (size_t)(t + 2) * (NN * FF));
#pragma unroll
            for (int ii = 0; ii < 4; ++ii) {
                int c = tid + 256 * ii;
                rau[2 * ii]     = xq[2 * c];
                rau[2 * ii + 1] = xq[2 * c + 1];
            }
        }
        __builtin_amdgcn_sched_barrier(0);   // pin load issue before the MFMA cluster

        // S4: matmul1  h2'[64, w-cols] = x_t @ Wc + 1*bc   (bias via acc init)
        f32x4 acc1[4][2];
#pragma unroll
        for (int rt = 0; rt < 4; ++rt)
#pragma unroll
            for (int ct = 0; ct < 2; ++ct)
                acc1[rt][ct] = bcs[ct];
#pragma unroll
        for (int kk = 0; kk < 4; ++kk) {
            f16x8 af[4];
#pragma unroll
            for (int rt = 0; rt < 4; ++rt)
                af[rt] = *(const f16x8*)(xh + (rt * 16 + l15) * XH_PITCH + kk * 32 + lg * 8);
#pragma unroll
            for (int rt = 0; rt < 4; ++rt)
#pragma unroll
                for (int ct = 0; ct < 2; ++ct)
                    acc1[rt][ct] = __builtin_amdgcn_mfma_f32_16x16x32_f16(
                        af[rt], wcf[ct][kk], acc1[rt][ct], 0, 0, 0);
        }
        BAR_LDS();         // all waves done reading xh — NO vmcnt drain

        // S5: per-wave transpose h2' -> LDS [col][node] (wave-private cols, no barrier)
#pragma unroll
        for (int rt = 0; rt < 4; ++rt)
#pragma unroll
            for (int ct = 0; ct < 2; ++ct) {
                f16x4 hv;
#pragma unroll
                for (int r = 0; r < 4; ++r) hv[r] = (f16)acc1[rt][ct][r];
                *(f16x4*)(h2t + (w * 32 + ct * 16 + l15) * H2_PITCH + rt * 16 + lg * 4) = hv;
            }

        // S7: matmul2 swapped: D = h2'^T * norm^T  (lane -> 4 consecutive out cols)
        f32x4 acc2[2][4];
#pragma unroll
        for (int ct = 0; ct < 2; ++ct)
#pragma unroll
            for (int rt = 0; rt < 4; ++rt)
                acc2[ct][rt] = bgf[ct];
#pragma unroll
        for (int kk = 0; kk < 2; ++kk) {
            f16x8 bf[2];
#pragma unroll
            for (int ct = 0; ct < 2; ++ct)
                bf[ct] = *(const f16x8*)(h2t + (w * 32 + ct * 16 + l15) * H2_PITCH + kk * 32 + lg * 8);
            f16x8 nl[4];
#pragma unroll
            for (int rt = 0; rt < 4; ++rt)
                nl[rt] = *(const f16x8*)(nsh + (rt * 16 + l15) * NM_PITCH + kk * 32 + lg * 8);
#pragma unroll
            for (int ct = 0; ct < 2; ++ct)
#pragma unroll
                for (int rt = 0; rt < 4; ++rt)
                    acc2[ct][rt] = __builtin_amdgcn_mfma_f32_16x16x32_f16(
                        bf[ct], nl[rt], acc2[ct][rt], 0, 0, 0);
        }

        // epilogue: store fp32 as float4 (full 128B line per row per wave);
        // stores stay in flight across the next iteration's barriers
        float* op = out + (size_t)t * (NN * OO);
#pragma unroll
        for (int rt = 0; rt < 4; ++rt)
#pragma unroll
            for (int ct = 0; ct < 2; ++ct)
                *(f32x4*)(op + (rt * 16 + l15) * OO + w * 32 + ct * 16 + lg * 4) = acc2[ct][rt];
    };

#pragma unroll 1
    for (int i = 0; i < TPB_T; i += 2) {
        body(raA, i);
        body(raB, i + 1);
    }
}

extern "C" void kernel_launch(void* const* d_in, const int* in_sizes, int n_in,
                              void* d_out, int out_size, void* d_ws, size_t ws_size,
                              hipStream_t stream)
{
    const float* x    = (const float*)d_in[0];
    const float* wenc = (const float*)d_in[1];
    const float* benc = (const float*)d_in[2];
    const float* wgcn = (const float*)d_in[3];
    const float* bgcn = (const float*)d_in[4];
    const int*   src  = (const int*)d_in[5];
    const int*   dst  = (const int*)d_in[6];
    const int E = in_sizes[5];

    // workspace layout: WcT f16 [128*128] (32768 B) | norm f16 [64*64] (8192 B) | bc f32 [128] (512 B)
    f16*   wctg  = (f16*)d_ws;
    f16*   normg = (f16*)((char*)d_ws + 32768);
    float* bcg   = (float*)((char*)d_ws + 32768 + 8192);

    prep_norm_kernel<<<1, 256, 0, stream>>>(src, dst, E, benc, wgcn, normg, bcg);
    prep_wc_kernel<<<OO / 2, 256, 0, stream>>>(wenc, wgcn, wctg);
    fused_kernel<<<T_STEPS / TPB_T, 256, 0, stream>>>(x, normg, wctg, bcg, bgcn, (float*)d_out);
}

// Round 6
// 128.711 us; speedup vs baseline: 1.0710x; 1.0026x over previous
//
#include <hip/hip_runtime.h>
#include <hip/hip_bf16.h>

#define T_STEPS 8192
#define NN 64
#define FF 128
#define HH 128
#define OO 128
#define TPB_T 8

typedef _Float16 f16;
typedef __attribute__((ext_vector_type(8))) _Float16 f16x8;
typedef __attribute__((ext_vector_type(4))) _Float16 f16x4;
typedef __attribute__((ext_vector_type(4))) float f32x4;

// LDS pitches chosen for <=2-way bank aliasing on ds_read_b128 (free per m136)
#define XH_PITCH 136   // f16 units; stride 68 dwords -> bank step 4, 2-way
#define H2_PITCH 72    // f16 units; stride 36 dwords -> bank step 4, 2-way
#define NM_PITCH 72    // norm tile in LDS, same geometry

// Raw barrier with NO vmcnt drain and NO "memory" clobber.
// r5's version had ::: "memory" on the waitcnt asm — an inline asm with a
// memory clobber is mayLoad/mayStore, which forces SIInsertWaitcnts to
// conservatively drain ALL outstanding VMEM (vmcnt(0)) before it, silently
// re-creating the __syncthreads() drain. Clobber-free volatile asm + raw
// s_barrier + sched_barrier(0) walls keep LDS ordering (nothing may be
// scheduled across sched_barrier(0); lgkmcnt(0) covers ds_write->barrier)
// while letting global loads/stores stay in flight across the barrier, and
// letting the compiler emit exact COUNTED vmcnt for the register prefetch.
#define BAR_LDS() do {                                        \
    __builtin_amdgcn_sched_barrier(0);                        \
    asm volatile("s_waitcnt lgkmcnt(0)");                     \
    __builtin_amdgcn_s_barrier();                             \
    __builtin_amdgcn_sched_barrier(0);                        \
} while (0)

// ---------------- prep: norm (f16) + bc = b_enc @ W_gcn (f32) ----------------
__global__ void prep_norm_kernel(const int* __restrict__ src, const int* __restrict__ dst, int E,
                                 const float* __restrict__ benc, const float* __restrict__ wgcn,
                                 f16* __restrict__ normg, float* __restrict__ bcg)
{
    __shared__ float A[NN * NN];
    __shared__ float din[NN], dout[NN];
    const int tid = threadIdx.x;
    for (int i = tid; i < NN * NN; i += 256) A[i] = 0.0f;
    __syncthreads();
    for (int e = tid; e < E; e += 256) atomicAdd(&A[dst[e] * NN + src[e]], 1.0f);
    __syncthreads();
    if (tid < NN) A[tid * NN + tid] += 1.0f;
    __syncthreads();
    if (tid < NN) {               // deg_in[i] = row sum
        float s = 0.f;
        for (int j = 0; j < NN; ++j) s += A[tid * NN + j];
        din[tid] = s;
    } else if (tid < 2 * NN) {    // deg_out[j] = col sum
        int j = tid - NN;
        float s = 0.f;
        for (int i = 0; i < NN; ++i) s += A[i * NN + j];
        dout[j] = s;
    }
    __syncthreads();
    if (tid < NN) {
        float ri = rsqrtf(din[tid]);
        for (int j = 0; j < NN; ++j)
            normg[tid * NN + j] = (f16)(A[tid * NN + j] * ri * rsqrtf(dout[j]));
    }
    if (tid >= 128) {             // bc[o] = b_enc @ W_gcn
        int o = tid - 128;
        float s = 0.f;
        for (int h = 0; h < HH; ++h) s += benc[h] * wgcn[h * OO + o];
        bcg[o] = s;
    }
}

// ---------------- prep: WcT[o][f] = (W_enc @ W_gcn)^T (f16) ----------------
__global__ void prep_wc_kernel(const float* __restrict__ wenc, const float* __restrict__ wgcn,
                               f16* __restrict__ wctg)
{
    int o = blockIdx.x * 2 + (threadIdx.x >> 7);
    int f = threadIdx.x & 127;
    float s = 0.f;
    for (int h = 0; h < HH; ++h) s += wenc[f * HH + h] * wgcn[h * OO + o];
    wctg[o * FF + f] = (f16)s;
}

// ---------------- fused main: out[t] = norm @ (x[t] @ Wc + 1*bc) + 1*bgcn ----------------
__global__ __launch_bounds__(256, 2) void fused_kernel(
    const float* __restrict__ x, const f16* __restrict__ normg,
    const f16* __restrict__ wctg, const float* __restrict__ bcg,
    const float* __restrict__ bgcn, float* __restrict__ out)
{
    __shared__ f16 xh[NN * XH_PITCH];    // x_t as f16, padded  (17408 B)
    __shared__ f16 h2t[OO * H2_PITCH];   // h2 transposed [col][node] (18432 B)
    __shared__ f16 nsh[NN * NM_PITCH];   // norm staged in LDS (9216 B)

    const int tid = threadIdx.x;
    const int lane = tid & 63;
    const int w = tid >> 6;        // wave 0..3 -> output cols w*32..w*32+31
    const int l15 = lane & 15;
    const int lg = lane >> 4;      // 0..3

    // stage norm into LDS once (covered by the first barrier)
    for (int c = tid; c < (NN * NN) / 8; c += 256) {
        int row = c >> 3, cb = (c & 7) * 8;
        *(f16x8*)(nsh + row * NM_PITCH + cb) = *(const f16x8*)(normg + row * NN + cb);
    }

    // loop-invariant register state
    f16x8 wcf[2][4];               // B-frags of Wc for this wave's col slice (32 VGPR)
#pragma unroll
    for (int ct = 0; ct < 2; ++ct)
#pragma unroll
        for (int kk = 0; kk < 4; ++kk)
            wcf[ct][kk] = *(const f16x8*)(wctg + (w * 32 + ct * 16 + l15) * FF + kk * 32 + lg * 8);

    f32x4 bcs[2];                  // bc splat per ct (acc1 init)
#pragma unroll
    for (int ct = 0; ct < 2; ++ct) {
        float v = bcg[w * 32 + ct * 16 + l15];
        bcs[ct][0] = v; bcs[ct][1] = v; bcs[ct][2] = v; bcs[ct][3] = v;
    }
    f32x4 bgf[2];                  // bgcn frag per ct (acc2 init)
#pragma unroll
    for (int ct = 0; ct < 2; ++ct)
        bgf[ct] = *(const f32x4*)(bgcn + w * 32 + ct * 16 + lg * 4);

    const int t0 = blockIdx.x * TPB_T;

    // depth-2 register prefetch: two named buffers (rule #20: no runtime indexing)
    float4 raA[8], raB[8];
    {
        const float4* xp0 = (const float4*)(x + (size_t)t0 * (NN * FF));
        const float4* xp1 = xp0 + (NN * FF) / 4;
#pragma unroll
        for (int ii = 0; ii < 4; ++ii) {
            int c = tid + 256 * ii;
            raA[2 * ii]     = xp0[2 * c];
            raA[2 * ii + 1] = xp0[2 * c + 1];
        }
#pragma unroll
        for (int ii = 0; ii < 4; ++ii) {
            int c = tid + 256 * ii;
            raB[2 * ii]     = xp1[2 * c];
            raB[2 * ii + 1] = xp1[2 * c + 1];
        }
    }

    // one t-iteration: consume `rau`, refill it for t+2
    auto body = [&](float4 (&rau)[8], int i) {
        const int t = t0 + i;

        // S1: convert + stage x_t into LDS (compiler emits exact counted vmcnt
        // for rau here now that no asm forces a drain)
#pragma unroll
        for (int ii = 0; ii < 4; ++ii) {
            int c = tid + 256 * ii;
            int row = c >> 4, k0 = (c & 15) * 8;
            float4 a = rau[2 * ii], b = rau[2 * ii + 1];
            f16x8 v;
            v[0] = (f16)a.x; v[1] = (f16)a.y; v[2] = (f16)a.z; v[3] = (f16)a.w;
            v[4] = (f16)b.x; v[5] = (f16)b.y; v[6] = (f16)b.z; v[7] = (f16)b.w;
            *(f16x8*)(xh + row * XH_PITCH + k0) = v;
        }
        BAR_LDS();         // xh (and, first iter, nsh) ready — no VMEM drain

        // S3: refill rau for t+2 (stays in flight across the next barriers)
        if (i + 2 < TPB_T) {
            const float4* xq = (const float4*)(x + (size_t)(t + 2) * (NN * FF));
#pragma unroll
            for (int ii = 0; ii < 4; ++ii) {
                int c = tid + 256 * ii;
                rau[2 * ii]     = xq[2 * c];
                rau[2 * ii + 1] = xq[2 * c + 1];
            }
        }
        __builtin_amdgcn_sched_barrier(0);   // pin load issue before the MFMA cluster

        // S4: matmul1  h2'[64, w-cols] = x_t @ Wc + 1*bc   (bias via acc init)
        f32x4 acc1[4][2];
#pragma unroll
        for (int rt = 0; rt < 4; ++rt)
#pragma unroll
            for (int ct = 0; ct < 2; ++ct)
                acc1[rt][ct] = bcs[ct];
#pragma unroll
        for (int kk = 0; kk < 4; ++kk) {
            f16x8 af[4];
#pragma unroll
            for (int rt = 0; rt < 4; ++rt)
                af[rt] = *(const f16x8*)(xh + (rt * 16 + l15) * XH_PITCH + kk * 32 + lg * 8);
#pragma unroll
            for (int rt = 0; rt < 4; ++rt)
#pragma unroll
                for (int ct = 0; ct < 2; ++ct)
                    acc1[rt][ct] = __builtin_amdgcn_mfma_f32_16x16x32_f16(
                        af[rt], wcf[ct][kk], acc1[rt][ct], 0, 0, 0);
        }
        BAR_LDS();         // all waves done reading xh — no VMEM drain

        // S5: per-wave transpose h2' -> LDS [col][node] (wave-private cols, no barrier)
#pragma unroll
        for (int rt = 0; rt < 4; ++rt)
#pragma unroll
            for (int ct = 0; ct < 2; ++ct) {
                f16x4 hv;
#pragma unroll
                for (int r = 0; r < 4; ++r) hv[r] = (f16)acc1[rt][ct][r];
                *(f16x4*)(h2t + (w * 32 + ct * 16 + l15) * H2_PITCH + rt * 16 + lg * 4) = hv;
            }

        // S7: matmul2 swapped: D = h2'^T * norm^T  (lane -> 4 consecutive out cols)
        f32x4 acc2[2][4];
#pragma unroll
        for (int ct = 0; ct < 2; ++ct)
#pragma unroll
            for (int rt = 0; rt < 4; ++rt)
                acc2[ct][rt] = bgf[ct];
#pragma unroll
        for (int kk = 0; kk < 2; ++kk) {
            f16x8 bf[2];
#pragma unroll
            for (int ct = 0; ct < 2; ++ct)
                bf[ct] = *(const f16x8*)(h2t + (w * 32 + ct * 16 + l15) * H2_PITCH + kk * 32 + lg * 8);
            f16x8 nl[4];
#pragma unroll
            for (int rt = 0; rt < 4; ++rt)
                nl[rt] = *(const f16x8*)(nsh + (rt * 16 + l15) * NM_PITCH + kk * 32 + lg * 8);
#pragma unroll
            for (int ct = 0; ct < 2; ++ct)
#pragma unroll
                for (int rt = 0; rt < 4; ++rt)
                    acc2[ct][rt] = __builtin_amdgcn_mfma_f32_16x16x32_f16(
                        bf[ct], nl[rt], acc2[ct][rt], 0, 0, 0);
        }

        // epilogue: store fp32 as float4 (full 128B line per row per wave);
        // stores stay in flight across the next iteration's barriers
        float* op = out + (size_t)t * (NN * OO);
#pragma unroll
        for (int rt = 0; rt < 4; ++rt)
#pragma unroll
            for (int ct = 0; ct < 2; ++ct)
                *(f32x4*)(op + (rt * 16 + l15) * OO + w * 32 + ct * 16 + lg * 4) = acc2[ct][rt];
    };

#pragma unroll 1
    for (int i = 0; i < TPB_T; i += 2) {
        body(raA, i);
        body(raB, i + 1);
    }
}

extern "C" void kernel_launch(void* const* d_in, const int* in_sizes, int n_in,
                              void* d_out, int out_size, void* d_ws, size_t ws_size,
                              hipStream_t stream)
{
    const float* x    = (const float*)d_in[0];
    const float* wenc = (const float*)d_in[1];
    const float* benc = (const float*)d_in[2];
    const float* wgcn = (const float*)d_in[3];
    const float* bgcn = (const float*)d_in[4];
    const int*   src  = (const int*)d_in[5];
    const int*   dst  = (const int*)d_in[6];
    const int E = in_sizes[5];

    // workspace layout: WcT f16 [128*128] (32768 B) | norm f16 [64*64] (8192 B) | bc f32 [128] (512 B)
    f16*   wctg  = (f16*)d_ws;
    f16*   normg = (f16*)((char*)d_ws + 32768);
    float* bcg   = (float*)((char*)d_ws + 32768 + 8192);

    prep_norm_kernel<<<1, 256, 0, stream>>>(src, dst, E, benc, wgcn, normg, bcg);
    prep_wc_kernel<<<OO / 2, 256, 0, stream>>>(wenc, wgcn, wctg);
    fused_kernel<<<T_STEPS / TPB_T, 256, 0, stream>>>(x, normg, wctg, bcg, bgcn, (float*)d_out);
}